// Round 1
// baseline (1488.343 us; speedup 1.0000x reference)
//
#include <hip/hip_runtime.h>
#include <math.h>

// ---------------------------------------------------------------------------
// HyperdimensionalNeuralNetwork — reduced to 6 GEMMs + fused epilogues.
//
// prob[j] = (1/d_in) * prod_t cos^2(hw[t,j,0])   (quantum state stays uniform
// along axis 1 -> roll terms cancel; only cos amplitude survives).
//
// Precision: split-bf16 (hi+lo) GEMM computing Ah*Wh + Ah*Wl + Al*Wh over 3
// K-segments -> fp32-equivalent accuracy with bf16 MFMA throughput (3x work).
// ---------------------------------------------------------------------------

typedef __attribute__((ext_vector_type(8))) __bf16 bfrag;
typedef __attribute__((ext_vector_type(4))) float f32x4;

__device__ __forceinline__ void gload_lds16(const void* g, void* l) {
  __builtin_amdgcn_global_load_lds(
      (__attribute__((address_space(1))) void*)g,
      (__attribute__((address_space(3))) void*)l, 16, 0, 0);
}

__device__ __forceinline__ f32x4 mfma16(bfrag a, bfrag b, f32x4 c) {
  return __builtin_amdgcn_mfma_f32_16x16x32_bf16(a, b, c, 0, 0, 0);
}

// ---------------------------------------------------------------------------
// GEMM: C[M,N] = act(A*W + bias).  A stored as [M][2K] bf16 (hi cols 0..K-1,
// lo cols K..2K-1).  Bt stored as [N][2K] bf16 (W^T, hi|lo along K).
// 3 K-segments: (hi,hi), (hi,lo), (lo,hi).
// EPI: 0 = relu -> bf16 hi|lo act buffer [M][2N]
//      1 = tanh -> bf16 hi|lo act buffer [M][2N]   (bias already includes prob)
//      2 = relu -> f32 out [M][N]
// Tile: BM=BN=128, BK=64; 4 waves (2x2), wave tile 64x64 (4x4 16x16 frags).
// LDS XOR swizzle: byte ^= (row&7)<<4 applied on global SOURCE at stage time
// (linear LDS dest, global_load_lds constraint) and on ds_read address.
// ---------------------------------------------------------------------------
template <int EPI>
__global__ __launch_bounds__(256) void hnn_gemm(
    const __bf16* __restrict__ A, const __bf16* __restrict__ Bt,
    const float* __restrict__ bias, __bf16* __restrict__ outAct,
    float* __restrict__ outF32, int M, int N, int K) {
  __shared__ __align__(1024) __bf16 As[128 * 64];
  __shared__ __align__(1024) __bf16 Bs[128 * 64];

  const int tid = threadIdx.x;
  const int lane = tid & 63;
  const int wid = tid >> 6;
  const int wr = wid >> 1, wc = wid & 1;
  const int lr = lane & 15, kg = lane >> 4;
  const int swz = (lr & 7) << 4;

  const size_t ldA = 2 * (size_t)K;  // row stride of A and Bt (hi|lo)
  const __bf16* gA = A + (size_t)(blockIdx.y * 128) * ldA;
  const __bf16* gB = Bt + (size_t)(blockIdx.x * 128) * ldA;

  // staging role for this wave
  const bool isA = (wid < 2);
  const __bf16* gsrc = isA ? gA : gB;
  __bf16* lbase = isA ? As : Bs;
  const int cbase = (wid & 1) * 8;      // chunk base (8 chunks of 1KB / wave)
  const int srow = lane >> 3;           // row within 8-row chunk
  const int sblk = lane & 7;            // physical 16B block in row
  const int lblk = sblk ^ srow;         // logical 16B block (inverse swizzle)

  f32x4 acc[4][4] = {};

  const int KT = K / 64;  // 64-wide k-tiles per segment
  int seg = 0, ko = 0;
  for (int it = 0; it < 3 * KT; ++it) {
    // segment k-offsets: seg0 (h,h): A hi, W hi; seg1 (h,l): A hi, W lo;
    // seg2 (l,h): A lo, W hi.
    const int kAoff = ((seg == 2) ? K : 0) + ko;
    const int kWoff = ((seg == 1) ? K : 0) + ko;
    const int ktw = isA ? kAoff : kWoff;

    // ---- stage 32KB (As+Bs) : 8 x global_load_lds(16B) per thread ----
#pragma unroll
    for (int i = 0; i < 8; ++i) {
      const int c = cbase + i;
      const int row = c * 8 + srow;
      gload_lds16(gsrc + (size_t)row * ldA + (size_t)(ktw + lblk * 8),
                  lbase + c * 512);
    }
    __syncthreads();

    // ---- compute: 2 k-steps of 32, 16 MFMA each ----
#pragma unroll
    for (int ks = 0; ks < 2; ++ks) {
      bfrag a[4], b[4];
      const int cb2 = (ks * 64 + kg * 16) ^ swz;
#pragma unroll
      for (int m = 0; m < 4; ++m) {
        const int row = wr * 64 + m * 16 + lr;
        a[m] = *(const bfrag*)((const char*)As + row * 128 + cb2);
      }
#pragma unroll
      for (int n = 0; n < 4; ++n) {
        const int row = wc * 64 + n * 16 + lr;
        b[n] = *(const bfrag*)((const char*)Bs + row * 128 + cb2);
      }
#pragma unroll
      for (int m = 0; m < 4; ++m)
#pragma unroll
        for (int n = 0; n < 4; ++n) acc[m][n] = mfma16(a[m], b[n], acc[m][n]);
    }
    __syncthreads();

    ko += 64;
    if (ko == K) { ko = 0; ++seg; }
  }

  // ---- epilogue.  C/D frag: col = lane&15, row = (lane>>4)*4 + reg ----
  const int rowBase = blockIdx.y * 128 + wr * 64;
  const int colBase = blockIdx.x * 128 + wc * 64;
#pragma unroll
  for (int n = 0; n < 4; ++n) {
    const int col = colBase + n * 16 + lr;
    const float bv = bias[col];
#pragma unroll
    for (int m = 0; m < 4; ++m) {
      const int row0 = rowBase + m * 16 + kg * 4;
#pragma unroll
      for (int r = 0; r < 4; ++r) {
        float v = acc[m][n][r] + bv;
        if (EPI == 1)
          v = tanhf(v);
        else
          v = fmaxf(v, 0.0f);
        const int row = row0 + r;
        if (EPI == 2) {
          outF32[(size_t)row * N + col] = v;
        } else {
          const __bf16 hi = (__bf16)v;
          const float lo = v - (float)hi;
          __bf16* o = outAct + (size_t)row * (2 * (size_t)N) + col;
          o[0] = hi;
          o[N] = (__bf16)lo;
        }
      }
    }
  }
}

// x [8192][1024] f32 -> act [8192][2048] bf16 hi|lo
__global__ __launch_bounds__(256) void xconv(const float* __restrict__ x,
                                             __bf16* __restrict__ out) {
  const size_t idx = (size_t)blockIdx.x * 256 + threadIdx.x;
  const int row = (int)(idx >> 10);
  const int col = (int)(idx & 1023);
  const float v = x[idx];
  const __bf16 hi = (__bf16)v;
  const float lo = v - (float)hi;
  __bf16* o = out + (size_t)row * 2048 + col;
  o[0] = hi;
  o[1024] = (__bf16)lo;
}

// W [K][N] f32 -> Wt [N][2K] bf16 hi|lo (transposed), 32x32 LDS tiles
__global__ __launch_bounds__(256) void wconv(const float* __restrict__ W,
                                             __bf16* __restrict__ Wt, int K,
                                             int N) {
  __shared__ float tile[32][33];
  const int tx = threadIdx.x, ty = threadIdx.y;
  const int n0 = blockIdx.x * 32, k0 = blockIdx.y * 32;
#pragma unroll
  for (int i = 0; i < 32; i += 8)
    tile[ty + i][tx] = W[(size_t)(k0 + ty + i) * N + n0 + tx];
  __syncthreads();
#pragma unroll
  for (int i = 0; i < 32; i += 8) {
    const int n = n0 + ty + i;
    const int k = k0 + tx;
    const float v = tile[tx][ty + i];
    const __bf16 hi = (__bf16)v;
    const float lo = v - (float)hi;
    __bf16* o = Wt + (size_t)n * (2 * (size_t)K) + k;
    o[0] = hi;
    o[K] = (__bf16)lo;
  }
}

// pbias[j] = cb[j] + (1/H) * prod_{t<5} cos^2(hw[t,j,0])
__global__ __launch_bounds__(256) void probk(const float* __restrict__ hw,
                                             const float* __restrict__ cb,
                                             float* __restrict__ pbias, int H) {
  const int j = blockIdx.x * 256 + threadIdx.x;
  if (j >= H) return;
  float p = 1.0f / (float)H;
#pragma unroll
  for (int t = 0; t < 5; ++t) {
    const float a = hw[(size_t)t * H * H + (size_t)j * H];
    const float c = cosf(a);
    p *= c * c;
  }
  pbias[j] = cb[j] + p;
}

extern "C" void kernel_launch(void* const* d_in, const int* in_sizes, int n_in,
                              void* d_out, int out_size, void* d_ws,
                              size_t ws_size, hipStream_t stream) {
  (void)in_sizes;
  (void)n_in;
  (void)out_size;
  (void)ws_size;
  const float* x = (const float*)d_in[0];
  const float* w0 = (const float*)d_in[1];
  const float* b0 = (const float*)d_in[2];
  const float* w1 = (const float*)d_in[3];
  const float* b1 = (const float*)d_in[4];
  const float* hw0 = (const float*)d_in[5];
  const float* cw0 = (const float*)d_in[6];
  const float* cb0 = (const float*)d_in[7];
  const float* w2 = (const float*)d_in[8];
  const float* b2 = (const float*)d_in[9];
  const float* hw1 = (const float*)d_in[10];
  const float* cw1 = (const float*)d_in[11];
  const float* cb1 = (const float*)d_in[12];
  const float* wf = (const float*)d_in[13];
  const float* bf = (const float*)d_in[14];

  char* ws = (char*)d_ws;
  __bf16* actA = (__bf16*)ws;                          // 64 MB  [8192][4096]
  __bf16* actB = (__bf16*)(ws + ((size_t)64 << 20));   // 64 MB
  char* p = ws + ((size_t)128 << 20);
  __bf16* wt0 = (__bf16*)p;  p += (size_t)2048 * 2048 * 2;   // [2048][2048]
  __bf16* wt1 = (__bf16*)p;  p += (size_t)2048 * 4096 * 2;   // [2048][4096]
  __bf16* wtc0 = (__bf16*)p; p += (size_t)2048 * 4096 * 2;
  __bf16* wt2 = (__bf16*)p;  p += (size_t)2048 * 4096 * 2;
  __bf16* wtc1 = (__bf16*)p; p += (size_t)2048 * 4096 * 2;
  __bf16* wtf = (__bf16*)p;  p += (size_t)1024 * 4096 * 2;   // [1024][4096]
  float* pb0 = (float*)p;    p += 2048 * 4;
  float* pb1 = (float*)p;    p += 2048 * 4;

  // conversions (weights restored each call -> reconvert each call)
  xconv<<<(8192 * 1024) / 256, 256, 0, stream>>>(x, actA);
  wconv<<<dim3(2048 / 32, 1024 / 32), dim3(32, 8), 0, stream>>>(w0, wt0, 1024,
                                                                2048);
  wconv<<<dim3(2048 / 32, 2048 / 32), dim3(32, 8), 0, stream>>>(w1, wt1, 2048,
                                                                2048);
  wconv<<<dim3(2048 / 32, 2048 / 32), dim3(32, 8), 0, stream>>>(cw0, wtc0,
                                                                2048, 2048);
  wconv<<<dim3(2048 / 32, 2048 / 32), dim3(32, 8), 0, stream>>>(w2, wt2, 2048,
                                                                2048);
  wconv<<<dim3(2048 / 32, 2048 / 32), dim3(32, 8), 0, stream>>>(cw1, wtc1,
                                                                2048, 2048);
  wconv<<<dim3(1024 / 32, 2048 / 32), dim3(32, 8), 0, stream>>>(wf, wtf, 2048,
                                                                1024);
  probk<<<8, 256, 0, stream>>>(hw0, cb0, pb0, 2048);
  probk<<<8, 256, 0, stream>>>(hw1, cb1, pb1, 2048);

  // 6-layer chain
  hnn_gemm<0><<<dim3(16, 64), 256, 0, stream>>>(actA, wt0, b0, actB, nullptr,
                                                8192, 2048, 1024);
  hnn_gemm<0><<<dim3(16, 64), 256, 0, stream>>>(actB, wt1, b1, actA, nullptr,
                                                8192, 2048, 2048);
  hnn_gemm<1><<<dim3(16, 64), 256, 0, stream>>>(actA, wtc0, pb0, actB, nullptr,
                                                8192, 2048, 2048);
  hnn_gemm<0><<<dim3(16, 64), 256, 0, stream>>>(actB, wt2, b2, actA, nullptr,
                                                8192, 2048, 2048);
  hnn_gemm<1><<<dim3(16, 64), 256, 0, stream>>>(actA, wtc1, pb1, actB, nullptr,
                                                8192, 2048, 2048);
  hnn_gemm<2><<<dim3(8, 64), 256, 0, stream>>>(actB, wtf, bf, nullptr,
                                               (float*)d_out, 8192, 1024, 2048);
}

// Round 2
// 1111.687 us; speedup vs baseline: 1.3388x; 1.3388x over previous
//
#include <hip/hip_runtime.h>
#include <math.h>

// ---------------------------------------------------------------------------
// HyperdimensionalNeuralNetwork — reduced to 6 GEMMs + fused epilogues.
//
// prob[j] = (1/d_in) * prod_t cos^2(hw[t,j,0])   (quantum state stays uniform
// along axis 1 -> roll terms cancel; only cos amplitude survives).
//
// Precision (R2): activations single bf16 [M][K]; W split hi|lo bf16 [N][2K].
// GEMM computes A*Wh + A*Wl over 2 K-segments (W f32-faithful; activation
// rounding ~2^-9 relative is the only bf16 loss). R1 (3-seg) absmax=1.95e-3.
// ---------------------------------------------------------------------------

typedef __attribute__((ext_vector_type(8))) __bf16 bfrag;
typedef __attribute__((ext_vector_type(4))) float f32x4;

__device__ __forceinline__ void gload_lds16(const void* g, void* l) {
  __builtin_amdgcn_global_load_lds(
      (__attribute__((address_space(1))) void*)g,
      (__attribute__((address_space(3))) void*)l, 16, 0, 0);
}

__device__ __forceinline__ f32x4 mfma16(bfrag a, bfrag b, f32x4 c) {
  return __builtin_amdgcn_mfma_f32_16x16x32_bf16(a, b, c, 0, 0, 0);
}

// ---------------------------------------------------------------------------
// GEMM: C[M,N] = act(A*W + bias).  A: [M][K] bf16.  Bt: [N][2K] bf16 (W^T,
// hi cols 0..K-1, lo cols K..2K-1).  2 K-segments: (A,Wh), (A,Wl).
// EPI: 0 = relu -> bf16 act [M][N]
//      1 = tanh -> bf16 act [M][N]   (bias already includes prob)
//      2 = relu -> f32 out [M][N]
// Tile: BM=BN=128, BK=64; 4 waves (2x2), wave tile 64x64 (4x4 16x16 frags).
// LDS XOR swizzle: byte ^= (row&7)<<4 applied on global SOURCE at stage time
// (linear LDS dest, global_load_lds constraint) and on ds_read address.
// ---------------------------------------------------------------------------
template <int EPI>
__global__ __launch_bounds__(256) void hnn_gemm(
    const __bf16* __restrict__ A, const __bf16* __restrict__ Bt,
    const float* __restrict__ bias, __bf16* __restrict__ outAct,
    float* __restrict__ outF32, int M, int N, int K) {
  __shared__ __align__(1024) __bf16 As[128 * 64];
  __shared__ __align__(1024) __bf16 Bs[128 * 64];

  const int tid = threadIdx.x;
  const int lane = tid & 63;
  const int wid = tid >> 6;
  const int wr = wid >> 1, wc = wid & 1;
  const int lr = lane & 15, kg = lane >> 4;
  const int swz = (lr & 7) << 4;

  const size_t ldA = (size_t)K;      // A row stride (single bf16)
  const size_t ldB = 2 * (size_t)K;  // Bt row stride (hi|lo)
  const __bf16* gA = A + (size_t)(blockIdx.y * 128) * ldA;
  const __bf16* gB = Bt + (size_t)(blockIdx.x * 128) * ldB;

  // staging role for this wave
  const bool isA = (wid < 2);
  const __bf16* gsrc = isA ? gA : gB;
  const size_t lds = isA ? ldA : ldB;
  __bf16* lbase = isA ? As : Bs;
  const int cbase = (wid & 1) * 8;      // chunk base (8 chunks of 1KB / wave)
  const int srow = lane >> 3;           // row within 8-row chunk
  const int sblk = lane & 7;            // physical 16B block in row
  const int lblk = sblk ^ srow;         // logical 16B block (inverse swizzle)

  f32x4 acc[4][4] = {};

  const int KT = K / 64;  // 64-wide k-tiles per segment
  int seg = 0, ko = 0;
  for (int it = 0; it < 2 * KT; ++it) {
    // A always reads hi range [0,K); W reads hi then lo range.
    const int kW = seg * K + ko;
    const int kt = isA ? ko : kW;

    // ---- stage 32KB (As+Bs) : 8 x global_load_lds(16B) per thread ----
#pragma unroll
    for (int i = 0; i < 8; ++i) {
      const int c = cbase + i;
      const int row = c * 8 + srow;
      gload_lds16(gsrc + (size_t)row * lds + (size_t)(kt + lblk * 8),
                  lbase + c * 512);
    }
    __syncthreads();

    // ---- compute: 2 k-steps of 32, 16 MFMA each ----
#pragma unroll
    for (int ks = 0; ks < 2; ++ks) {
      bfrag a[4], b[4];
      const int cb2 = (ks * 64 + kg * 16) ^ swz;
#pragma unroll
      for (int m = 0; m < 4; ++m) {
        const int row = wr * 64 + m * 16 + lr;
        a[m] = *(const bfrag*)((const char*)As + row * 128 + cb2);
      }
#pragma unroll
      for (int n = 0; n < 4; ++n) {
        const int row = wc * 64 + n * 16 + lr;
        b[n] = *(const bfrag*)((const char*)Bs + row * 128 + cb2);
      }
#pragma unroll
      for (int m = 0; m < 4; ++m)
#pragma unroll
        for (int n = 0; n < 4; ++n) acc[m][n] = mfma16(a[m], b[n], acc[m][n]);
    }
    __syncthreads();

    ko += 64;
    if (ko == K) { ko = 0; ++seg; }
  }

  // ---- epilogue.  C/D frag: col = lane&15, row = (lane>>4)*4 + reg ----
  const int rowBase = blockIdx.y * 128 + wr * 64;
  const int colBase = blockIdx.x * 128 + wc * 64;
#pragma unroll
  for (int n = 0; n < 4; ++n) {
    const int col = colBase + n * 16 + lr;
    const float bv = bias[col];
#pragma unroll
    for (int m = 0; m < 4; ++m) {
      const int row0 = rowBase + m * 16 + kg * 4;
#pragma unroll
      for (int r = 0; r < 4; ++r) {
        float v = acc[m][n][r] + bv;
        if (EPI == 1)
          v = tanhf(v);
        else
          v = fmaxf(v, 0.0f);
        const int row = row0 + r;
        if (EPI == 2) {
          outF32[(size_t)row * N + col] = v;
        } else {
          outAct[(size_t)row * N + col] = (__bf16)v;
        }
      }
    }
  }
}

// x [8192][1024] f32 -> bf16 [8192][1024]
__global__ __launch_bounds__(256) void xconv(const float* __restrict__ x,
                                             __bf16* __restrict__ out) {
  const size_t idx = (size_t)blockIdx.x * 256 + threadIdx.x;
  out[idx] = (__bf16)x[idx];
}

// W [K][N] f32 -> Wt [N][2K] bf16 hi|lo (transposed), 32x32 LDS tiles
__global__ __launch_bounds__(256) void wconv(const float* __restrict__ W,
                                             __bf16* __restrict__ Wt, int K,
                                             int N) {
  __shared__ float tile[32][33];
  const int tx = threadIdx.x, ty = threadIdx.y;
  const int n0 = blockIdx.x * 32, k0 = blockIdx.y * 32;
#pragma unroll
  for (int i = 0; i < 32; i += 8)
    tile[ty + i][tx] = W[(size_t)(k0 + ty + i) * N + n0 + tx];
  __syncthreads();
#pragma unroll
  for (int i = 0; i < 32; i += 8) {
    const int n = n0 + ty + i;
    const int k = k0 + tx;
    const float v = tile[tx][ty + i];
    const __bf16 hi = (__bf16)v;
    const float lo = v - (float)hi;
    __bf16* o = Wt + (size_t)n * (2 * (size_t)K) + k;
    o[0] = hi;
    o[K] = (__bf16)lo;
  }
}

// pbias[j] = cb[j] + (1/H) * prod_{t<5} cos^2(hw[t,j,0])
__global__ __launch_bounds__(256) void probk(const float* __restrict__ hw,
                                             const float* __restrict__ cb,
                                             float* __restrict__ pbias, int H) {
  const int j = blockIdx.x * 256 + threadIdx.x;
  if (j >= H) return;
  float p = 1.0f / (float)H;
#pragma unroll
  for (int t = 0; t < 5; ++t) {
    const float a = hw[(size_t)t * H * H + (size_t)j * H];
    const float c = cosf(a);
    p *= c * c;
  }
  pbias[j] = cb[j] + p;
}

extern "C" void kernel_launch(void* const* d_in, const int* in_sizes, int n_in,
                              void* d_out, int out_size, void* d_ws,
                              size_t ws_size, hipStream_t stream) {
  (void)in_sizes;
  (void)n_in;
  (void)out_size;
  (void)ws_size;
  const float* x = (const float*)d_in[0];
  const float* w0 = (const float*)d_in[1];
  const float* b0 = (const float*)d_in[2];
  const float* w1 = (const float*)d_in[3];
  const float* b1 = (const float*)d_in[4];
  const float* hw0 = (const float*)d_in[5];
  const float* cw0 = (const float*)d_in[6];
  const float* cb0 = (const float*)d_in[7];
  const float* w2 = (const float*)d_in[8];
  const float* b2 = (const float*)d_in[9];
  const float* hw1 = (const float*)d_in[10];
  const float* cw1 = (const float*)d_in[11];
  const float* cb1 = (const float*)d_in[12];
  const float* wf = (const float*)d_in[13];
  const float* bf = (const float*)d_in[14];

  char* ws = (char*)d_ws;
  __bf16* actA = (__bf16*)ws;                          // 64 MB slot
  __bf16* actB = (__bf16*)(ws + ((size_t)64 << 20));   // 64 MB slot
  char* p = ws + ((size_t)128 << 20);
  __bf16* wt0 = (__bf16*)p;  p += (size_t)2048 * 2048 * 2;   // [2048][2048]
  __bf16* wt1 = (__bf16*)p;  p += (size_t)2048 * 4096 * 2;   // [2048][4096]
  __bf16* wtc0 = (__bf16*)p; p += (size_t)2048 * 4096 * 2;
  __bf16* wt2 = (__bf16*)p;  p += (size_t)2048 * 4096 * 2;
  __bf16* wtc1 = (__bf16*)p; p += (size_t)2048 * 4096 * 2;
  __bf16* wtf = (__bf16*)p;  p += (size_t)1024 * 4096 * 2;   // [1024][4096]
  float* pb0 = (float*)p;    p += 2048 * 4;
  float* pb1 = (float*)p;    p += 2048 * 4;

  // conversions (inputs restored each call -> reconvert each call)
  xconv<<<(8192 * 1024) / 256, 256, 0, stream>>>(x, actA);
  wconv<<<dim3(2048 / 32, 1024 / 32), dim3(32, 8), 0, stream>>>(w0, wt0, 1024,
                                                                2048);
  wconv<<<dim3(2048 / 32, 2048 / 32), dim3(32, 8), 0, stream>>>(w1, wt1, 2048,
                                                                2048);
  wconv<<<dim3(2048 / 32, 2048 / 32), dim3(32, 8), 0, stream>>>(cw0, wtc0,
                                                                2048, 2048);
  wconv<<<dim3(2048 / 32, 2048 / 32), dim3(32, 8), 0, stream>>>(w2, wt2, 2048,
                                                                2048);
  wconv<<<dim3(2048 / 32, 2048 / 32), dim3(32, 8), 0, stream>>>(cw1, wtc1,
                                                                2048, 2048);
  wconv<<<dim3(1024 / 32, 2048 / 32), dim3(32, 8), 0, stream>>>(wf, wtf, 2048,
                                                                1024);
  probk<<<8, 256, 0, stream>>>(hw0, cb0, pb0, 2048);
  probk<<<8, 256, 0, stream>>>(hw1, cb1, pb1, 2048);

  // 6-layer chain
  hnn_gemm<0><<<dim3(16, 64), 256, 0, stream>>>(actA, wt0, b0, actB, nullptr,
                                                8192, 2048, 1024);
  hnn_gemm<0><<<dim3(16, 64), 256, 0, stream>>>(actB, wt1, b1, actA, nullptr,
                                                8192, 2048, 2048);
  hnn_gemm<1><<<dim3(16, 64), 256, 0, stream>>>(actA, wtc0, pb0, actB, nullptr,
                                                8192, 2048, 2048);
  hnn_gemm<0><<<dim3(16, 64), 256, 0, stream>>>(actB, wt2, b2, actA, nullptr,
                                                8192, 2048, 2048);
  hnn_gemm<1><<<dim3(16, 64), 256, 0, stream>>>(actA, wtc1, pb1, actB, nullptr,
                                                8192, 2048, 2048);
  hnn_gemm<2><<<dim3(8, 64), 256, 0, stream>>>(actB, wtf, bf, nullptr,
                                               (float*)d_out, 8192, 1024, 2048);
}

// Round 3
// 912.672 us; speedup vs baseline: 1.6308x; 1.2181x over previous
//
#include <hip/hip_runtime.h>
#include <math.h>

// ---------------------------------------------------------------------------
// HyperdimensionalNeuralNetwork — reduced to 6 GEMMs + fused epilogues.
//
// prob[j] = (1/d_in) * prod_t cos^2(hw[t,j,0])   (quantum state stays uniform
// along axis 1 -> roll terms cancel; only cos amplitude survives).
//
// Precision: activations single bf16 [M][K]; W split hi|lo bf16 [N][2K].
// GEMM computes A*Wh + A*Wl over 2 K-segments. R2 absmax = 3.9e-3 (thr 1.25e-2).
//
// R3: 256x256 tile, 512 thr (8 waves 2Mx4N), BK=64, K-tile double-buffered
// 128KB LDS, 4-phase interleave (quadrant MFMA + per-phase half-tile stage
// issue), setprio around MFMA, one __syncthreads drain per K-tile.
// ---------------------------------------------------------------------------

typedef __attribute__((ext_vector_type(8))) __bf16 bfrag;
typedef __attribute__((ext_vector_type(4))) float f32x4;

__device__ __forceinline__ void gload_lds16(const void* g, void* l) {
  __builtin_amdgcn_global_load_lds(
      (__attribute__((address_space(1))) void*)g,
      (__attribute__((address_space(3))) void*)l, 16, 0, 0);
}

__device__ __forceinline__ f32x4 mfma16(bfrag a, bfrag b, f32x4 c) {
  return __builtin_amdgcn_mfma_f32_16x16x32_bf16(a, b, c, 0, 0, 0);
}

// ---------------------------------------------------------------------------
// A: [M][K] bf16.  Bt: [N][2K] bf16 (W^T, hi|lo along K).  Keff = 2K.
// EPI: 0 = relu->bf16, 1 = tanh->bf16 (bias includes prob), 2 = relu->f32.
// LDS XOR swizzle (row&7)<<4 on bytes: pre-swizzled global source at stage,
// swizzled address on ds_read (both-sides rule).
// ---------------------------------------------------------------------------
template <int EPI>
__global__ __launch_bounds__(512, 2) void hnn_gemm(
    const __bf16* __restrict__ A, const __bf16* __restrict__ Bt,
    const float* __restrict__ bias, __bf16* __restrict__ outAct,
    float* __restrict__ outF32, int M, int N, int K) {
  __shared__ __align__(1024) char smem[131072];  // 2 slots x (A 32K | B 32K)

  const int tid = threadIdx.x;
  const int lane = tid & 63;
  const int wid = tid >> 6;   // 0..7
  const int wr = wid >> 2;    // 0..1  M-half of tile (128 rows)
  const int wc = wid & 3;     // 0..3  N-quarter (64 cols)
  const int lr = lane & 15, kg = lane >> 4;
  const int swz = (lr & 7) << 4;
  const int c0 = (kg * 16) ^ swz;        // k-step 0 byte col
  const int c1 = (64 + kg * 16) ^ swz;   // k-step 1 byte col

  // XCD-aware bijective block swizzle (nwg % 8 == 0 for all our grids)
  const int nwg = gridDim.x * gridDim.y;
  const int bid = blockIdx.y * gridDim.x + blockIdx.x;
  const int cpx = nwg >> 3;
  const int sid = (bid & 7) * cpx + (bid >> 3);
  const int bx = sid % gridDim.x;
  const int by = sid / gridDim.x;

  const size_t ldA = (size_t)K;
  const size_t ldB = 2 * (size_t)K;

  // staging constants: thread covers 16B blocks (row=tid>>3, blk=tid&7) and
  // (+64 rows) of each 128x64 half-tile; source pre-swizzled via lblk.
  const int srow = tid >> 3;                    // 0..63
  const int lblk = (tid & 7) ^ (srow & 7);      // logical 16B block
  const __bf16* pA = A + ((size_t)(by * 256 + srow)) * ldA + lblk * 8;
  const __bf16* pB = Bt + ((size_t)(bx * 256 + srow)) * ldB + lblk * 8;
  const int dst0 = tid * 16;  // per-thread byte offset in half-tile (wave-linear)

  f32x4 acc[8][4] = {};

  const int KT2 = (2 * K) >> 6;  // K-tiles over Keff

  // ---- prologue: stage K-tile 0 into slot 0 ----
  {
    char* Ad = smem;
    char* Bd = smem + 32768;
    gload_lds16(pA, Ad + dst0);
    gload_lds16(pA + 64 * ldA, Ad + dst0 + 8192);
    gload_lds16(pA + 128 * ldA, Ad + 16384 + dst0);
    gload_lds16(pA + 192 * ldA, Ad + 16384 + dst0 + 8192);
    gload_lds16(pB, Bd + dst0);
    gload_lds16(pB + 64 * ldB, Bd + dst0 + 8192);
    gload_lds16(pB + 128 * ldB, Bd + 16384 + dst0);
    gload_lds16(pB + 192 * ldB, Bd + 16384 + dst0 + 8192);
  }
  __syncthreads();

  const int arow = wr * 128 + lr;  // + m*16
  const int brow = wc * 64 + lr;   // + n*16

  for (int t = 0; t < KT2; ++t) {
    const int cur = t & 1;
    const char* Ab = smem + cur * 65536;
    const char* Bb = Ab + 32768;
    char* Adn = smem + (cur ^ 1) * 65536;
    char* Bdn = Adn + 32768;
    const int tn = (t + 1 < KT2) ? t + 1 : t;  // clamp: last group restages (unread)
    const int kAn = (tn << 6) & (K - 1);       // A wraps over 2 segments
    const int kBn = tn << 6;                   // Bt spans 2K cols

    bfrag am[4][2], bn0[2][2], bn1[2][2];

    // ============ phase 1: Q(m0,n0); stage A-half0(t+1) ============
#pragma unroll
    for (int mi = 0; mi < 4; ++mi) {
      const int r = arow + mi * 16;
      am[mi][0] = *(const bfrag*)(Ab + r * 128 + c0);
      am[mi][1] = *(const bfrag*)(Ab + r * 128 + c1);
    }
#pragma unroll
    for (int ni = 0; ni < 2; ++ni) {
      const int r = brow + ni * 16;
      bn0[ni][0] = *(const bfrag*)(Bb + r * 128 + c0);
      bn0[ni][1] = *(const bfrag*)(Bb + r * 128 + c1);
    }
    gload_lds16(pA + kAn, Adn + dst0);
    gload_lds16(pA + 64 * ldA + kAn, Adn + dst0 + 8192);
    __builtin_amdgcn_s_barrier();
    __builtin_amdgcn_s_setprio(1);
#pragma unroll
    for (int ks = 0; ks < 2; ++ks)
#pragma unroll
      for (int mi = 0; mi < 4; ++mi)
#pragma unroll
        for (int ni = 0; ni < 2; ++ni)
          acc[mi][ni] = mfma16(am[mi][ks], bn0[ni][ks], acc[mi][ni]);
    __builtin_amdgcn_s_setprio(0);
    __builtin_amdgcn_s_barrier();

    // ============ phase 2: Q(m0,n1); stage A-half1(t+1) ============
#pragma unroll
    for (int ni = 0; ni < 2; ++ni) {
      const int r = brow + (2 + ni) * 16;
      bn1[ni][0] = *(const bfrag*)(Bb + r * 128 + c0);
      bn1[ni][1] = *(const bfrag*)(Bb + r * 128 + c1);
    }
    gload_lds16(pA + 128 * ldA + kAn, Adn + 16384 + dst0);
    gload_lds16(pA + 192 * ldA + kAn, Adn + 16384 + dst0 + 8192);
    __builtin_amdgcn_s_barrier();
    __builtin_amdgcn_s_setprio(1);
#pragma unroll
    for (int ks = 0; ks < 2; ++ks)
#pragma unroll
      for (int mi = 0; mi < 4; ++mi)
#pragma unroll
        for (int ni = 0; ni < 2; ++ni)
          acc[mi][2 + ni] = mfma16(am[mi][ks], bn1[ni][ks], acc[mi][2 + ni]);
    __builtin_amdgcn_s_setprio(0);
    __builtin_amdgcn_s_barrier();

    // ============ phase 3: Q(m1,n1); stage B-half0(t+1) ============
#pragma unroll
    for (int mi = 0; mi < 4; ++mi) {
      const int r = arow + (4 + mi) * 16;
      am[mi][0] = *(const bfrag*)(Ab + r * 128 + c0);
      am[mi][1] = *(const bfrag*)(Ab + r * 128 + c1);
    }
    gload_lds16(pB + kBn, Bdn + dst0);
    gload_lds16(pB + 64 * ldB + kBn, Bdn + dst0 + 8192);
    __builtin_amdgcn_s_barrier();
    __builtin_amdgcn_s_setprio(1);
#pragma unroll
    for (int ks = 0; ks < 2; ++ks)
#pragma unroll
      for (int mi = 0; mi < 4; ++mi)
#pragma unroll
        for (int ni = 0; ni < 2; ++ni)
          acc[4 + mi][2 + ni] =
              mfma16(am[mi][ks], bn1[ni][ks], acc[4 + mi][2 + ni]);
    __builtin_amdgcn_s_setprio(0);
    __builtin_amdgcn_s_barrier();

    // ============ phase 4: Q(m1,n0); stage B-half1(t+1) ============
    gload_lds16(pB + 128 * ldB + kBn, Bdn + 16384 + dst0);
    gload_lds16(pB + 192 * ldB + kBn, Bdn + 16384 + dst0 + 8192);
    __builtin_amdgcn_s_barrier();
    __builtin_amdgcn_s_setprio(1);
#pragma unroll
    for (int ks = 0; ks < 2; ++ks)
#pragma unroll
      for (int mi = 0; mi < 4; ++mi)
#pragma unroll
        for (int ni = 0; ni < 2; ++ni)
          acc[4 + mi][ni] = mfma16(am[mi][ks], bn0[ni][ks], acc[4 + mi][ni]);
    __builtin_amdgcn_s_setprio(0);
    __syncthreads();  // full drain (vmcnt+lgkm) once per K-tile: slot swap safe
  }

  // ---- epilogue.  C/D frag: col = lane&15, row = (lane>>4)*4 + reg ----
  const int rowBase = by * 256 + wr * 128;
  const int colBase = bx * 256 + wc * 64;
#pragma unroll
  for (int n = 0; n < 4; ++n) {
    const int col = colBase + n * 16 + lr;
    const float bv = bias[col];
#pragma unroll
    for (int m = 0; m < 8; ++m) {
      const int row0 = rowBase + m * 16 + kg * 4;
#pragma unroll
      for (int r = 0; r < 4; ++r) {
        float v = acc[m][n][r] + bv;
        if (EPI == 1)
          v = tanhf(v);
        else
          v = fmaxf(v, 0.0f);
        const int row = row0 + r;
        if (EPI == 2) {
          outF32[(size_t)row * N + col] = v;
        } else {
          outAct[(size_t)row * N + col] = (__bf16)v;
        }
      }
    }
  }
}

// x [8192][1024] f32 -> bf16 [8192][1024]
__global__ __launch_bounds__(256) void xconv(const float* __restrict__ x,
                                             __bf16* __restrict__ out) {
  const size_t idx = (size_t)blockIdx.x * 256 + threadIdx.x;
  out[idx] = (__bf16)x[idx];
}

// W [K][N] f32 -> Wt [N][2K] bf16 hi|lo (transposed), 32x32 LDS tiles
__global__ __launch_bounds__(256) void wconv(const float* __restrict__ W,
                                             __bf16* __restrict__ Wt, int K,
                                             int N) {
  __shared__ float tile[32][33];
  const int tx = threadIdx.x, ty = threadIdx.y;
  const int n0 = blockIdx.x * 32, k0 = blockIdx.y * 32;
#pragma unroll
  for (int i = 0; i < 32; i += 8)
    tile[ty + i][tx] = W[(size_t)(k0 + ty + i) * N + n0 + tx];
  __syncthreads();
#pragma unroll
  for (int i = 0; i < 32; i += 8) {
    const int n = n0 + ty + i;
    const int k = k0 + tx;
    const float v = tile[tx][ty + i];
    const __bf16 hi = (__bf16)v;
    const float lo = v - (float)hi;
    __bf16* o = Wt + (size_t)n * (2 * (size_t)K) + k;
    o[0] = hi;
    o[K] = (__bf16)lo;
  }
}

// pbias[j] = cb[j] + (1/H) * prod_{t<5} cos^2(hw[t,j,0])
__global__ __launch_bounds__(256) void probk(const float* __restrict__ hw,
                                             const float* __restrict__ cb,
                                             float* __restrict__ pbias, int H) {
  const int j = blockIdx.x * 256 + threadIdx.x;
  if (j >= H) return;
  float p = 1.0f / (float)H;
#pragma unroll
  for (int t = 0; t < 5; ++t) {
    const float a = hw[(size_t)t * H * H + (size_t)j * H];
    const float c = cosf(a);
    p *= c * c;
  }
  pbias[j] = cb[j] + p;
}

extern "C" void kernel_launch(void* const* d_in, const int* in_sizes, int n_in,
                              void* d_out, int out_size, void* d_ws,
                              size_t ws_size, hipStream_t stream) {
  (void)in_sizes;
  (void)n_in;
  (void)out_size;
  (void)ws_size;
  const float* x = (const float*)d_in[0];
  const float* w0 = (const float*)d_in[1];
  const float* b0 = (const float*)d_in[2];
  const float* w1 = (const float*)d_in[3];
  const float* b1 = (const float*)d_in[4];
  const float* hw0 = (const float*)d_in[5];
  const float* cw0 = (const float*)d_in[6];
  const float* cb0 = (const float*)d_in[7];
  const float* w2 = (const float*)d_in[8];
  const float* b2 = (const float*)d_in[9];
  const float* hw1 = (const float*)d_in[10];
  const float* cw1 = (const float*)d_in[11];
  const float* cb1 = (const float*)d_in[12];
  const float* wf = (const float*)d_in[13];
  const float* bf = (const float*)d_in[14];

  char* ws = (char*)d_ws;
  __bf16* actA = (__bf16*)ws;                          // 64 MB slot
  __bf16* actB = (__bf16*)(ws + ((size_t)64 << 20));   // 64 MB slot
  char* p = ws + ((size_t)128 << 20);
  __bf16* wt0 = (__bf16*)p;  p += (size_t)2048 * 2048 * 2;   // [2048][2048]
  __bf16* wt1 = (__bf16*)p;  p += (size_t)2048 * 4096 * 2;   // [2048][4096]
  __bf16* wtc0 = (__bf16*)p; p += (size_t)2048 * 4096 * 2;
  __bf16* wt2 = (__bf16*)p;  p += (size_t)2048 * 4096 * 2;
  __bf16* wtc1 = (__bf16*)p; p += (size_t)2048 * 4096 * 2;
  __bf16* wtf = (__bf16*)p;  p += (size_t)1024 * 4096 * 2;   // [1024][4096]
  float* pb0 = (float*)p;    p += 2048 * 4;
  float* pb1 = (float*)p;    p += 2048 * 4;

  // conversions (inputs restored each call -> reconvert each call)
  xconv<<<(8192 * 1024) / 256, 256, 0, stream>>>(x, actA);
  wconv<<<dim3(2048 / 32, 1024 / 32), dim3(32, 8), 0, stream>>>(w0, wt0, 1024,
                                                                2048);
  wconv<<<dim3(2048 / 32, 2048 / 32), dim3(32, 8), 0, stream>>>(w1, wt1, 2048,
                                                                2048);
  wconv<<<dim3(2048 / 32, 2048 / 32), dim3(32, 8), 0, stream>>>(cw0, wtc0,
                                                                2048, 2048);
  wconv<<<dim3(2048 / 32, 2048 / 32), dim3(32, 8), 0, stream>>>(w2, wt2, 2048,
                                                                2048);
  wconv<<<dim3(2048 / 32, 2048 / 32), dim3(32, 8), 0, stream>>>(cw1, wtc1,
                                                                2048, 2048);
  wconv<<<dim3(1024 / 32, 2048 / 32), dim3(32, 8), 0, stream>>>(wf, wtf, 2048,
                                                                1024);
  probk<<<8, 256, 0, stream>>>(hw0, cb0, pb0, 2048);
  probk<<<8, 256, 0, stream>>>(hw1, cb1, pb1, 2048);

  // 6-layer chain (grid: x = N/256, y = M/256; 512 threads)
  hnn_gemm<0><<<dim3(8, 32), 512, 0, stream>>>(actA, wt0, b0, actB, nullptr,
                                               8192, 2048, 1024);
  hnn_gemm<0><<<dim3(8, 32), 512, 0, stream>>>(actB, wt1, b1, actA, nullptr,
                                               8192, 2048, 2048);
  hnn_gemm<1><<<dim3(8, 32), 512, 0, stream>>>(actA, wtc0, pb0, actB, nullptr,
                                               8192, 2048, 2048);
  hnn_gemm<0><<<dim3(8, 32), 512, 0, stream>>>(actB, wt2, b2, actA, nullptr,
                                               8192, 2048, 2048);
  hnn_gemm<1><<<dim3(8, 32), 512, 0, stream>>>(actA, wtc1, pb1, actB, nullptr,
                                               8192, 2048, 2048);
  hnn_gemm<2><<<dim3(4, 32), 512, 0, stream>>>(actB, wtf, bf, nullptr,
                                               (float*)d_out, 8192, 1024, 2048);
}